// Round 6
// baseline (340.393 us; speedup 1.0000x reference)
//
#include <hip/hip_runtime.h>

// RAConv: reciprocal-attention graph conv, N=100K nodes, E=1.6M edges, D=64, fp32.
// Strategy: counting-sort edges by dst (CSR), then wave-per-node register
// accumulation (zero float atomics), then fused bf16-MFMA epilogue GEMM.
//   attn normalization folded: msg = (sum_e x_src*exp(logit)) / (sum_e exp(logit))
//   var  = E[x^2] - E[x]^2   (exact rewrite of double scatter-mean)
// R2: node_gather -> split-half wave layout.
// R3: gemm -> mfma_f32_16x16x32_bf16, A=[x|msg|var] staged bf16 in LDS.
// R4: hist+scatter XCD-partitioned (blockIdx&7 owns a dst range) -> L2-local
//     atomics + full-line write combining.
// R5: gather datapath bf16 (xb precomputed, 4 edges/wave, msgvar bf16).
// R6: partition computation was a 64-bit divide by runtime N (~40 inst x 25.6M
//     execs = the hidden 170us in hist+scatter). Replace with host-computed
//     float scale: p = (int)(dst * (8.0f/N)) -- 2 inst, identical in both
//     kernels (only mutual consistency + p in [0,8) is required).

static inline size_t ws_align(size_t x) { return (x + 255) & ~size_t(255); }

typedef __attribute__((ext_vector_type(8))) short bf16x8;
typedef __attribute__((ext_vector_type(4))) float f32x4;

__device__ __forceinline__ unsigned short f2bf(float f) {
    unsigned u = __builtin_bit_cast(unsigned, f);
    u += 0x7FFFu + ((u >> 16) & 1u);          // RNE
    return (unsigned short)(u >> 16);
}
__device__ __forceinline__ float bfhi(int d) {          // high bf16 of dword
    return __builtin_bit_cast(float, (unsigned)d & 0xFFFF0000u);
}
__device__ __forceinline__ float bflo(int d) {          // low bf16 of dword
    return __builtin_bit_cast(float, (unsigned)d << 16);
}

__global__ void cast_kernel(const float* __restrict__ x, unsigned short* __restrict__ xb, int n4) {
    int i = blockIdx.x * blockDim.x + threadIdx.x;
    if (i < n4) {
        float4 v = ((const float4*)x)[i];
        ushort4 h; h.x = f2bf(v.x); h.y = f2bf(v.y); h.z = f2bf(v.z); h.w = f2bf(v.w);
        ((ushort4*)xb)[i] = h;
    }
}

// Partitioned histogram: only edges whose dst falls in this block's partition.
// Partition via float scale (host-computed 8/N): 2 VALU inst, consistent
// across kernels, p in [0,7] guaranteed (max product 8*(N-1)/N < 8).
__global__ void __launch_bounds__(256) hist_kernel(const int* __restrict__ ei,
                                                   int* __restrict__ deg, int E,
                                                   float inv8N) {
    int part = blockIdx.x & 7;
    int vb   = blockIdx.x >> 3;
    int nvb  = gridDim.x >> 3;
    const int* dstp = ei + E;
    for (int base = vb * 256; base < E; base += nvb * 256) {
        int e = base + threadIdx.x;
        if (e < E) {
            int dst = dstp[e];
            int p = min((int)((float)dst * inv8N), 7);
            if (p == part) atomicAdd(&deg[dst], 1);
        }
    }
}

// Per-block exclusive scan (256 elems) + block sums.
__global__ void scan_a_kernel(const int* __restrict__ deg, int* __restrict__ rs,
                              int* __restrict__ bsum, int N) {
    __shared__ int t[256];
    int i = blockIdx.x * 256 + threadIdx.x;
    int v = (i < N) ? deg[i] : 0;
    t[threadIdx.x] = v;
    __syncthreads();
    for (int off = 1; off < 256; off <<= 1) {
        int u = (threadIdx.x >= (unsigned)off) ? t[threadIdx.x - off] : 0;
        __syncthreads();
        t[threadIdx.x] += u;
        __syncthreads();
    }
    if (i < N) rs[i] = t[threadIdx.x] - v;      // exclusive within block
    if (threadIdx.x == 255) bsum[blockIdx.x] = t[255];
}

// Exclusive scan of block sums (nb <= 512).
__global__ void scan_b_kernel(int* __restrict__ bsum, int nb) {
    __shared__ int t[512];
    int i = threadIdx.x;
    int v = (i < nb) ? bsum[i] : 0;
    t[i] = v;
    __syncthreads();
    for (int off = 1; off < 512; off <<= 1) {
        int u = (i >= off) ? t[i - off] : 0;
        __syncthreads();
        t[i] += u;
        __syncthreads();
    }
    if (i < nb) bsum[i] = t[i] - v;             // exclusive
}

__global__ void scan_c_kernel(int* __restrict__ rs, const int* __restrict__ bsum,
                              int* __restrict__ cursor, int N, int E) {
    int i = blockIdx.x * blockDim.x + threadIdx.x;
    if (i < N) {
        int v = rs[i] + bsum[i >> 8];
        rs[i] = v;
        cursor[i] = v;
    }
    if (i == 0) rs[N] = E;
}

// Partitioned scatter: same partition rule as hist.
__global__ void __launch_bounds__(256) scatter_kernel(const int* __restrict__ ei,
                                                      int* __restrict__ cursor,
                                                      int* __restrict__ srcs, int E,
                                                      float inv8N) {
    int part = blockIdx.x & 7;
    int vb   = blockIdx.x >> 3;
    int nvb  = gridDim.x >> 3;
    const int* dstp = ei + E;
    for (int base = vb * 256; base < E; base += nvb * 256) {
        int e = base + threadIdx.x;
        if (e < E) {
            int dst = dstp[e];
            int p = min((int)((float)dst * inv8N), 7);
            if (p == part) {
                int pos = atomicAdd(&cursor[dst], 1);
                srcs[pos] = ei[e];
            }
        }
    }
}

// One wave per node, 4 edges per batch: 16-lane group g handles edge g, lane
// q=lane&15 holds features 4q..4q+3 (2 packed-bf16 dwords). Logit dot:
// bf16 src x fp32 xn, 4-step butterfly within group. Cross-group combine once.
__global__ void __launch_bounds__(256) node_gather_kernel(
        const float* __restrict__ x, const unsigned short* __restrict__ xb,
        const int* __restrict__ rs, const int* __restrict__ srcs,
        unsigned short* __restrict__ msgvar, int N) {
    int w = (blockIdx.x * blockDim.x + threadIdx.x) >> 6;
    if (w >= N) return;
    int lane = threadIdx.x & 63;
    int q = lane & 15;                 // feature block (features 4q..4q+3)
    int g = lane >> 4;                 // edge slot within batch of 4
    int s = rs[w], e = rs[w + 1];
    const int2* xb2 = (const int2*)xb;            // row = 16 int2 (128 B)
    float4 xn = ((const float4*)(x + (size_t)w * 64))[q];
    float den = 0.f;
    float4 sx = {0,0,0,0}, ssq = {0,0,0,0}, sme = {0,0,0,0};

    auto edge4 = [&](int p) {                     // 4 full edges
        int i0 = srcs[p], i1 = srcs[p + 1], i2 = srcs[p + 2], i3 = srcs[p + 3];
        int r = (g < 2) ? (g == 0 ? i0 : i1) : (g == 2 ? i2 : i3);
        int2 d = xb2[(size_t)r * 16 + q];
        float f0 = bflo(d.x), f1 = bfhi(d.x), f2 = bflo(d.y), f3 = bfhi(d.y);
        float t = fmaf(f0, xn.x, fmaf(f1, xn.y, fmaf(f2, xn.z, f3 * xn.w)));
        #pragma unroll
        for (int off = 1; off < 16; off <<= 1) t += __shfl_xor(t, off, 64);
        float ex = __expf(t * 0.125f);
        den += ex;
        sx.x += f0; sx.y += f1; sx.z += f2; sx.w += f3;
        ssq.x = fmaf(f0, f0, ssq.x); ssq.y = fmaf(f1, f1, ssq.y);
        ssq.z = fmaf(f2, f2, ssq.z); ssq.w = fmaf(f3, f3, ssq.w);
        sme.x = fmaf(ex, f0, sme.x); sme.y = fmaf(ex, f1, sme.y);
        sme.z = fmaf(ex, f2, sme.z); sme.w = fmaf(ex, f3, sme.w);
    };

    int p = s;
    for (; p + 8 <= e; p += 8) { edge4(p); edge4(p + 4); }
    if (p + 4 <= e) { edge4(p); p += 4; }
    if (p < e) {                                  // masked tail (1-3 edges)
        float wt = (p + g < e) ? 1.f : 0.f;
        int r = srcs[min(p + g, e - 1)];
        int2 d = xb2[(size_t)r * 16 + q];
        float f0 = bflo(d.x), f1 = bfhi(d.x), f2 = bflo(d.y), f3 = bfhi(d.y);
        float t = fmaf(f0, xn.x, fmaf(f1, xn.y, fmaf(f2, xn.z, f3 * xn.w)));
        #pragma unroll
        for (int off = 1; off < 16; off <<= 1) t += __shfl_xor(t, off, 64);
        float ex = __expf(t * 0.125f) * wt;
        float w0 = f0 * wt, w1 = f1 * wt, w2 = f2 * wt, w3 = f3 * wt;
        den += ex;
        sx.x += w0; sx.y += w1; sx.z += w2; sx.w += w3;
        ssq.x = fmaf(w0, f0, ssq.x); ssq.y = fmaf(w1, f1, ssq.y);
        ssq.z = fmaf(w2, f2, ssq.z); ssq.w = fmaf(w3, f3, ssq.w);
        sme.x = fmaf(ex, f0, sme.x); sme.y = fmaf(ex, f1, sme.y);
        sme.z = fmaf(ex, f2, sme.z); sme.w = fmaf(ex, f3, sme.w);
    }
    // combine the 4 groups (lanes q, q+16, q+32, q+48 hold the same features)
    #pragma unroll
    for (int off = 16; off < 64; off <<= 1) {
        den   += __shfl_xor(den,   off, 64);
        sx.x  += __shfl_xor(sx.x,  off, 64); sx.y  += __shfl_xor(sx.y,  off, 64);
        sx.z  += __shfl_xor(sx.z,  off, 64); sx.w  += __shfl_xor(sx.w,  off, 64);
        ssq.x += __shfl_xor(ssq.x, off, 64); ssq.y += __shfl_xor(ssq.y, off, 64);
        ssq.z += __shfl_xor(ssq.z, off, 64); ssq.w += __shfl_xor(ssq.w, off, 64);
        sme.x += __shfl_xor(sme.x, off, 64); sme.y += __shfl_xor(sme.y, off, 64);
        sme.z += __shfl_xor(sme.z, off, 64); sme.w += __shfl_xor(sme.w, off, 64);
    }
    if (lane < 16) {
        float inv = 1.f / fmaxf((float)(e - s), 1.f);
        float invden = (den > 0.f) ? (1.f / den) : 0.f;
        float mx = sx.x * inv, my = sx.y * inv, mz = sx.z * inv, mw = sx.w * inv;
        ushort4 hm, hv;
        hm.x = f2bf(sme.x * invden); hm.y = f2bf(sme.y * invden);
        hm.z = f2bf(sme.z * invden); hm.w = f2bf(sme.w * invden);
        hv.x = f2bf(ssq.x * inv - mx * mx); hv.y = f2bf(ssq.y * inv - my * my);
        hv.z = f2bf(ssq.z * inv - mz * mz); hv.w = f2bf(ssq.w * inv - mw * mw);
        *(ushort4*)&msgvar[(size_t)w * 128 + 4 * q]      = hm;
        *(ushort4*)&msgvar[(size_t)w * 128 + 64 + 4 * q] = hv;
    }
}

// MFMA epilogue GEMM: out = A @ Wcat^T + b, A = [x | msg | var] (N x 192).
__global__ void __launch_bounds__(256) gemm_kernel(
        const float* __restrict__ x, const unsigned short* __restrict__ msgvar,
        const float* __restrict__ Ws, const float* __restrict__ bs,
        const float* __restrict__ Wn, const float* __restrict__ bn,
        const float* __restrict__ Wv, const float* __restrict__ bv,
        float* __restrict__ out, int N) {
    __shared__ unsigned short As[64 * 200];
    int tid = threadIdx.x;
    int nbase = blockIdx.x * 64;

    // stage x part: 64 rows x 16 float4 -> bf16
    #pragma unroll
    for (int i = 0; i < 4; ++i) {
        int idx = i * 256 + tid;
        int row = idx >> 4, c = idx & 15;
        int n = min(nbase + row, N - 1);
        float4 v = ((const float4*)(x + (size_t)n * 64))[c];
        ushort4 h; h.x = f2bf(v.x); h.y = f2bf(v.y); h.z = f2bf(v.z); h.w = f2bf(v.w);
        *(ushort4*)&As[row * 200 + c * 4] = h;
    }
    // stage msgvar part: 64 rows x 32 ushort4 (bf16, [msg|var] contiguous)
    #pragma unroll
    for (int i = 0; i < 8; ++i) {
        int idx = i * 256 + tid;
        int row = idx >> 5, c = idx & 31;
        int n = min(nbase + row, N - 1);
        ushort4 h = ((const ushort4*)(msgvar + (size_t)n * 128))[c];
        *(ushort4*)&As[row * 200 + 64 + c * 4] = h;
    }

    int lane = tid & 63;
    int wv = tid >> 6;                  // feature tile (wave id)
    int j = lane & 15, quad = lane >> 4;
    int jg = wv * 16 + j;               // global output feature

    // B fragments: 6 K-steps, lane holds W[jg][k0..k0+7] as bf16
    const float* Wm0[3] = {Ws, Wn, Wv};
    bf16x8 bfrag[6];
    #pragma unroll
    for (int ks = 0; ks < 6; ++ks) {
        const float* W = Wm0[ks >> 1];
        int k0 = (ks & 1) * 32 + quad * 8;
        const float4* p = (const float4*)(W + (size_t)jg * 64 + k0);
        float4 a = p[0], b = p[1];
        bf16x8 f;
        f[0] = (short)f2bf(a.x); f[1] = (short)f2bf(a.y);
        f[2] = (short)f2bf(a.z); f[3] = (short)f2bf(a.w);
        f[4] = (short)f2bf(b.x); f[5] = (short)f2bf(b.y);
        f[6] = (short)f2bf(b.z); f[7] = (short)f2bf(b.w);
        bfrag[ks] = f;
    }
    float bias = bs[jg] + bn[jg] + bv[jg];
    f32x4 acc[4];
    #pragma unroll
    for (int nt = 0; nt < 4; ++nt) { acc[nt][0] = bias; acc[nt][1] = bias; acc[nt][2] = bias; acc[nt][3] = bias; }

    __syncthreads();

    #pragma unroll
    for (int nt = 0; nt < 4; ++nt) {
        #pragma unroll
        for (int ks = 0; ks < 6; ++ks) {
            const bf16x8* ap = (const bf16x8*)&As[(nt * 16 + j) * 200 + ks * 32 + quad * 8];
            acc[nt] = __builtin_amdgcn_mfma_f32_16x16x32_bf16(*ap, bfrag[ks], acc[nt], 0, 0, 0);
        }
    }

    // D: node = nbase + nt*16 + quad*4 + r, col = jg
    #pragma unroll
    for (int nt = 0; nt < 4; ++nt) {
        #pragma unroll
        for (int r = 0; r < 4; ++r) {
            int node = nbase + nt * 16 + quad * 4 + r;
            if (node < N) out[(size_t)node * 64 + jg] = acc[nt][r];
        }
    }
}

extern "C" void kernel_launch(void* const* d_in, const int* in_sizes, int n_in,
                              void* d_out, int out_size, void* d_ws, size_t ws_size,
                              hipStream_t stream) {
    const float* x  = (const float*)d_in[0];
    const int*   ei = (const int*)d_in[1];
    const float* Ws = (const float*)d_in[2];
    const float* bs = (const float*)d_in[3];
    const float* Wn = (const float*)d_in[4];
    const float* bn = (const float*)d_in[5];
    const float* Wv = (const float*)d_in[6];
    const float* bv = (const float*)d_in[7];
    float* out = (float*)d_out;

    int N  = in_sizes[0] / 64;
    int E  = in_sizes[1] / 2;
    int NB = (N + 255) / 256;
    float inv8N = (float)(8.0 / (double)N);

    char* wsp = (char*)d_ws;
    size_t off = 0;
    int* deg    = (int*)(wsp + off); off += ws_align((size_t)N * 4);
    int* rs     = (int*)(wsp + off); off += ws_align((size_t)(N + 1) * 4);
    int* cursor = (int*)(wsp + off); off += ws_align((size_t)N * 4);
    int* bsumi  = (int*)(wsp + off); off += ws_align((size_t)NB * 4);
    int* srcs   = (int*)(wsp + off); off += ws_align((size_t)E * 4);
    unsigned short* msgvar = (unsigned short*)(wsp + off); off += ws_align((size_t)N * 128 * 2);
    unsigned short* xb     = (unsigned short*)(wsp + off); off += ws_align((size_t)N * 64 * 2);

    hipMemsetAsync(deg, 0, (size_t)N * 4, stream);
    cast_kernel<<<(N * 16 + 255) / 256, 256, 0, stream>>>(x, xb, N * 16);
    hist_kernel<<<2048, 256, 0, stream>>>(ei, deg, E, inv8N);
    scan_a_kernel<<<NB, 256, 0, stream>>>(deg, rs, bsumi, N);
    scan_b_kernel<<<1, 512, 0, stream>>>(bsumi, NB);
    scan_c_kernel<<<(N + 255) / 256, 256, 0, stream>>>(rs, bsumi, cursor, N, E);
    scatter_kernel<<<2048, 256, 0, stream>>>(ei, cursor, srcs, E, inv8N);
    node_gather_kernel<<<((size_t)N * 64 + 255) / 256, 256, 0, stream>>>(x, xb, rs, srcs, msgvar, N);
    gemm_kernel<<<(N + 63) / 64, 256, 0, stream>>>(x, msgvar, Ws, bs, Wn, bn, Wv, bv, out, N);
}

// Round 7
// 308.365 us; speedup vs baseline: 1.1039x; 1.1039x over previous
//
#include <hip/hip_runtime.h>

// RAConv: reciprocal-attention graph conv, N=100K nodes, E=1.6M edges, D=64, fp32.
// Strategy: counting-sort edges by dst (CSR), then wave-per-node register
// accumulation, then fused bf16-MFMA epilogue GEMM.
//   attn normalization folded: msg = (sum_e x_src*exp(logit)) / (sum_e exp(logit))
//   var  = E[x^2] - E[x]^2   (exact rewrite of double scatter-mean)
// R2: node_gather -> split-half wave layout.
// R3: gemm -> mfma_f32_16x16x32_bf16, A=[x|msg|var] staged bf16 in LDS.
// R4: scatter XCD-partitioned for srcs write combining.
// R5: gather datapath bf16 (xb precomputed, 4 edges/wave, msgvar bf16).
// R6: float-scale partition (neutral -> atomics, not VALU, are the cost).
// R7: atomic-serialization fix. hist -> 8 histogram copies (per-line atomic
//     chains 256->32) + records rank[e] = returned old count. scan_a converts
//     copies to per-copy exclusive offsets in place. scatter -> ZERO atomics:
//     pos = rs[dst] + copyoff[c][dst] + rank[e], c=(e>>8)&7 in both kernels.

static inline size_t ws_align(size_t x) { return (x + 255) & ~size_t(255); }

typedef __attribute__((ext_vector_type(8))) short bf16x8;
typedef __attribute__((ext_vector_type(4))) float f32x4;

__device__ __forceinline__ unsigned short f2bf(float f) {
    unsigned u = __builtin_bit_cast(unsigned, f);
    u += 0x7FFFu + ((u >> 16) & 1u);          // RNE
    return (unsigned short)(u >> 16);
}
__device__ __forceinline__ float bfhi(int d) {          // high bf16 of dword
    return __builtin_bit_cast(float, (unsigned)d & 0xFFFF0000u);
}
__device__ __forceinline__ float bflo(int d) {          // low bf16 of dword
    return __builtin_bit_cast(float, (unsigned)d << 16);
}

__global__ void cast_kernel(const float* __restrict__ x, unsigned short* __restrict__ xb, int n4) {
    int i = blockIdx.x * blockDim.x + threadIdx.x;
    if (i < n4) {
        float4 v = ((const float4*)x)[i];
        ushort4 h; h.x = f2bf(v.x); h.y = f2bf(v.y); h.z = f2bf(v.z); h.w = f2bf(v.w);
        ((ushort4*)xb)[i] = h;
    }
}

// 8-copy histogram + rank recording. Copy c = (e>>8)&7 is wave-uniform
// (= blockIdx&7 for 256-thread blocks) and reproducible in scatter.
// Returned old value = edge's rank within (copy, dst).
__global__ void __launch_bounds__(256) hist_kernel(const int* __restrict__ ei,
                                                   int* __restrict__ deg,
                                                   int* __restrict__ rank, int E, int N) {
    int e = blockIdx.x * 256 + threadIdx.x;
    if (e < E) {
        int dst = ei[E + e];
        int c = (e >> 8) & 7;
        rank[e] = atomicAdd(&deg[c * N + dst], 1);
    }
}

// Per-node: fold 8 copies -> total degree, converting copies in place to
// exclusive per-copy offsets. Then per-block exclusive scan of totals.
__global__ void scan_a_kernel(int* __restrict__ deg, int* __restrict__ rs,
                              int* __restrict__ bsum, int N) {
    __shared__ int t[256];
    int i = blockIdx.x * 256 + threadIdx.x;
    int total = 0;
    if (i < N) {
        int acc = 0;
        #pragma unroll
        for (int c = 0; c < 8; ++c) {
            int v = deg[c * N + i];
            deg[c * N + i] = acc;          // exclusive prefix across copies
            acc += v;
        }
        total = acc;
    }
    t[threadIdx.x] = total;
    __syncthreads();
    for (int off = 1; off < 256; off <<= 1) {
        int u = (threadIdx.x >= (unsigned)off) ? t[threadIdx.x - off] : 0;
        __syncthreads();
        t[threadIdx.x] += u;
        __syncthreads();
    }
    if (i < N) rs[i] = t[threadIdx.x] - total;   // exclusive within block
    if (threadIdx.x == 255) bsum[blockIdx.x] = t[255];
}

// Exclusive scan of block sums (nb <= 512).
__global__ void scan_b_kernel(int* __restrict__ bsum, int nb) {
    __shared__ int t[512];
    int i = threadIdx.x;
    int v = (i < nb) ? bsum[i] : 0;
    t[i] = v;
    __syncthreads();
    for (int off = 1; off < 512; off <<= 1) {
        int u = (i >= off) ? t[i - off] : 0;
        __syncthreads();
        t[i] += u;
        __syncthreads();
    }
    if (i < nb) bsum[i] = t[i] - v;             // exclusive
}

__global__ void scan_c_kernel(int* __restrict__ rs, const int* __restrict__ bsum,
                              int N, int E) {
    int i = blockIdx.x * blockDim.x + threadIdx.x;
    if (i < N) rs[i] += bsum[i >> 8];
    if (i == 0) rs[N] = E;
}

// Atomic-free scatter: pos = rs[dst] + copyoff[c][dst] + rank[e].
// 8-way dst-partition retained only for srcs write-combining locality.
__global__ void __launch_bounds__(256) scatter_kernel(const int* __restrict__ ei,
                                                      const int* __restrict__ rs,
                                                      const int* __restrict__ deg,
                                                      const int* __restrict__ rank,
                                                      int* __restrict__ srcs, int E, int N,
                                                      float inv8N) {
    int part = blockIdx.x & 7;
    int vb   = blockIdx.x >> 3;
    int nvb  = gridDim.x >> 3;
    const int* dstp = ei + E;
    for (int base = vb * 256; base < E; base += nvb * 256) {
        int e = base + threadIdx.x;
        if (e < E) {
            int dst = dstp[e];
            int p = min((int)((float)dst * inv8N), 7);
            if (p == part) {
                int c = (e >> 8) & 7;                  // same rule as hist
                int pos = rs[dst] + deg[c * N + dst] + rank[e];
                srcs[pos] = ei[e];
            }
        }
    }
}

// One wave per node, 4 edges per batch: 16-lane group g handles edge g, lane
// q=lane&15 holds features 4q..4q+3 (2 packed-bf16 dwords). Logit dot:
// bf16 src x fp32 xn, 4-step butterfly within group. Cross-group combine once.
__global__ void __launch_bounds__(256) node_gather_kernel(
        const float* __restrict__ x, const unsigned short* __restrict__ xb,
        const int* __restrict__ rs, const int* __restrict__ srcs,
        unsigned short* __restrict__ msgvar, int N) {
    int w = (blockIdx.x * blockDim.x + threadIdx.x) >> 6;
    if (w >= N) return;
    int lane = threadIdx.x & 63;
    int q = lane & 15;                 // feature block (features 4q..4q+3)
    int g = lane >> 4;                 // edge slot within batch of 4
    int s = rs[w], e = rs[w + 1];
    const int2* xb2 = (const int2*)xb;            // row = 16 int2 (128 B)
    float4 xn = ((const float4*)(x + (size_t)w * 64))[q];
    float den = 0.f;
    float4 sx = {0,0,0,0}, ssq = {0,0,0,0}, sme = {0,0,0,0};

    auto edge4 = [&](int p) {                     // 4 full edges
        int i0 = srcs[p], i1 = srcs[p + 1], i2 = srcs[p + 2], i3 = srcs[p + 3];
        int r = (g < 2) ? (g == 0 ? i0 : i1) : (g == 2 ? i2 : i3);
        int2 d = xb2[(size_t)r * 16 + q];
        float f0 = bflo(d.x), f1 = bfhi(d.x), f2 = bflo(d.y), f3 = bfhi(d.y);
        float t = fmaf(f0, xn.x, fmaf(f1, xn.y, fmaf(f2, xn.z, f3 * xn.w)));
        #pragma unroll
        for (int off = 1; off < 16; off <<= 1) t += __shfl_xor(t, off, 64);
        float ex = __expf(t * 0.125f);
        den += ex;
        sx.x += f0; sx.y += f1; sx.z += f2; sx.w += f3;
        ssq.x = fmaf(f0, f0, ssq.x); ssq.y = fmaf(f1, f1, ssq.y);
        ssq.z = fmaf(f2, f2, ssq.z); ssq.w = fmaf(f3, f3, ssq.w);
        sme.x = fmaf(ex, f0, sme.x); sme.y = fmaf(ex, f1, sme.y);
        sme.z = fmaf(ex, f2, sme.z); sme.w = fmaf(ex, f3, sme.w);
    };

    int p = s;
    for (; p + 8 <= e; p += 8) { edge4(p); edge4(p + 4); }
    if (p + 4 <= e) { edge4(p); p += 4; }
    if (p < e) {                                  // masked tail (1-3 edges)
        float wt = (p + g < e) ? 1.f : 0.f;
        int r = srcs[min(p + g, e - 1)];
        int2 d = xb2[(size_t)r * 16 + q];
        float f0 = bflo(d.x), f1 = bfhi(d.x), f2 = bflo(d.y), f3 = bfhi(d.y);
        float t = fmaf(f0, xn.x, fmaf(f1, xn.y, fmaf(f2, xn.z, f3 * xn.w)));
        #pragma unroll
        for (int off = 1; off < 16; off <<= 1) t += __shfl_xor(t, off, 64);
        float ex = __expf(t * 0.125f) * wt;
        float w0 = f0 * wt, w1 = f1 * wt, w2 = f2 * wt, w3 = f3 * wt;
        den += ex;
        sx.x += w0; sx.y += w1; sx.z += w2; sx.w += w3;
        ssq.x = fmaf(w0, f0, ssq.x); ssq.y = fmaf(w1, f1, ssq.y);
        ssq.z = fmaf(w2, f2, ssq.z); ssq.w = fmaf(w3, f3, ssq.w);
        sme.x = fmaf(ex, f0, sme.x); sme.y = fmaf(ex, f1, sme.y);
        sme.z = fmaf(ex, f2, sme.z); sme.w = fmaf(ex, f3, sme.w);
    }
    // combine the 4 groups (lanes q, q+16, q+32, q+48 hold the same features)
    #pragma unroll
    for (int off = 16; off < 64; off <<= 1) {
        den   += __shfl_xor(den,   off, 64);
        sx.x  += __shfl_xor(sx.x,  off, 64); sx.y  += __shfl_xor(sx.y,  off, 64);
        sx.z  += __shfl_xor(sx.z,  off, 64); sx.w  += __shfl_xor(sx.w,  off, 64);
        ssq.x += __shfl_xor(ssq.x, off, 64); ssq.y += __shfl_xor(ssq.y, off, 64);
        ssq.z += __shfl_xor(ssq.z, off, 64); ssq.w += __shfl_xor(ssq.w, off, 64);
        sme.x += __shfl_xor(sme.x, off, 64); sme.y += __shfl_xor(sme.y, off, 64);
        sme.z += __shfl_xor(sme.z, off, 64); sme.w += __shfl_xor(sme.w, off, 64);
    }
    if (lane < 16) {
        float inv = 1.f / fmaxf((float)(e - s), 1.f);
        float invden = (den > 0.f) ? (1.f / den) : 0.f;
        float mx = sx.x * inv, my = sx.y * inv, mz = sx.z * inv, mw = sx.w * inv;
        ushort4 hm, hv;
        hm.x = f2bf(sme.x * invden); hm.y = f2bf(sme.y * invden);
        hm.z = f2bf(sme.z * invden); hm.w = f2bf(sme.w * invden);
        hv.x = f2bf(ssq.x * inv - mx * mx); hv.y = f2bf(ssq.y * inv - my * my);
        hv.z = f2bf(ssq.z * inv - mz * mz); hv.w = f2bf(ssq.w * inv - mw * mw);
        *(ushort4*)&msgvar[(size_t)w * 128 + 4 * q]      = hm;
        *(ushort4*)&msgvar[(size_t)w * 128 + 64 + 4 * q] = hv;
    }
}

// MFMA epilogue GEMM: out = A @ Wcat^T + b, A = [x | msg | var] (N x 192).
__global__ void __launch_bounds__(256) gemm_kernel(
        const float* __restrict__ x, const unsigned short* __restrict__ msgvar,
        const float* __restrict__ Ws, const float* __restrict__ bs,
        const float* __restrict__ Wn, const float* __restrict__ bn,
        const float* __restrict__ Wv, const float* __restrict__ bv,
        float* __restrict__ out, int N) {
    __shared__ unsigned short As[64 * 200];
    int tid = threadIdx.x;
    int nbase = blockIdx.x * 64;

    // stage x part: 64 rows x 16 float4 -> bf16
    #pragma unroll
    for (int i = 0; i < 4; ++i) {
        int idx = i * 256 + tid;
        int row = idx >> 4, c = idx & 15;
        int n = min(nbase + row, N - 1);
        float4 v = ((const float4*)(x + (size_t)n * 64))[c];
        ushort4 h; h.x = f2bf(v.x); h.y = f2bf(v.y); h.z = f2bf(v.z); h.w = f2bf(v.w);
        *(ushort4*)&As[row * 200 + c * 4] = h;
    }
    // stage msgvar part: 64 rows x 32 ushort4 (bf16, [msg|var] contiguous)
    #pragma unroll
    for (int i = 0; i < 8; ++i) {
        int idx = i * 256 + tid;
        int row = idx >> 5, c = idx & 31;
        int n = min(nbase + row, N - 1);
        ushort4 h = ((const ushort4*)(msgvar + (size_t)n * 128))[c];
        *(ushort4*)&As[row * 200 + 64 + c * 4] = h;
    }

    int lane = tid & 63;
    int wv = tid >> 6;                  // feature tile (wave id)
    int j = lane & 15, quad = lane >> 4;
    int jg = wv * 16 + j;               // global output feature

    // B fragments: 6 K-steps, lane holds W[jg][k0..k0+7] as bf16
    const float* Wm0[3] = {Ws, Wn, Wv};
    bf16x8 bfrag[6];
    #pragma unroll
    for (int ks = 0; ks < 6; ++ks) {
        const float* W = Wm0[ks >> 1];
        int k0 = (ks & 1) * 32 + quad * 8;
        const float4* p = (const float4*)(W + (size_t)jg * 64 + k0);
        float4 a = p[0], b = p[1];
        bf16x8 f;
        f[0] = (short)f2bf(a.x); f[1] = (short)f2bf(a.y);
        f[2] = (short)f2bf(a.z); f[3] = (short)f2bf(a.w);
        f[4] = (short)f2bf(b.x); f[5] = (short)f2bf(b.y);
        f[6] = (short)f2bf(b.z); f[7] = (short)f2bf(b.w);
        bfrag[ks] = f;
    }
    float bias = bs[jg] + bn[jg] + bv[jg];
    f32x4 acc[4];
    #pragma unroll
    for (int nt = 0; nt < 4; ++nt) { acc[nt][0] = bias; acc[nt][1] = bias; acc[nt][2] = bias; acc[nt][3] = bias; }

    __syncthreads();

    #pragma unroll
    for (int nt = 0; nt < 4; ++nt) {
        #pragma unroll
        for (int ks = 0; ks < 6; ++ks) {
            const bf16x8* ap = (const bf16x8*)&As[(nt * 16 + j) * 200 + ks * 32 + quad * 8];
            acc[nt] = __builtin_amdgcn_mfma_f32_16x16x32_bf16(*ap, bfrag[ks], acc[nt], 0, 0, 0);
        }
    }

    // D: node = nbase + nt*16 + quad*4 + r, col = jg
    #pragma unroll
    for (int nt = 0; nt < 4; ++nt) {
        #pragma unroll
        for (int r = 0; r < 4; ++r) {
            int node = nbase + nt * 16 + quad * 4 + r;
            if (node < N) out[(size_t)node * 64 + jg] = acc[nt][r];
        }
    }
}

extern "C" void kernel_launch(void* const* d_in, const int* in_sizes, int n_in,
                              void* d_out, int out_size, void* d_ws, size_t ws_size,
                              hipStream_t stream) {
    const float* x  = (const float*)d_in[0];
    const int*   ei = (const int*)d_in[1];
    const float* Ws = (const float*)d_in[2];
    const float* bs = (const float*)d_in[3];
    const float* Wn = (const float*)d_in[4];
    const float* bn = (const float*)d_in[5];
    const float* Wv = (const float*)d_in[6];
    const float* bv = (const float*)d_in[7];
    float* out = (float*)d_out;

    int N  = in_sizes[0] / 64;
    int E  = in_sizes[1] / 2;
    int NB = (N + 255) / 256;
    float inv8N = (float)(8.0 / (double)N);

    char* wsp = (char*)d_ws;
    size_t off = 0;
    int* deg    = (int*)(wsp + off); off += ws_align((size_t)N * 8 * 4);   // 8 copies
    int* rs     = (int*)(wsp + off); off += ws_align((size_t)(N + 1) * 4);
    int* bsumi  = (int*)(wsp + off); off += ws_align((size_t)NB * 4);
    int* srcs   = (int*)(wsp + off); off += ws_align((size_t)E * 4);
    int* rank   = (int*)(wsp + off); off += ws_align((size_t)E * 4);
    unsigned short* msgvar = (unsigned short*)(wsp + off); off += ws_align((size_t)N * 128 * 2);
    unsigned short* xb     = (unsigned short*)(wsp + off); off += ws_align((size_t)N * 64 * 2);

    hipMemsetAsync(deg, 0, (size_t)N * 8 * 4, stream);
    cast_kernel<<<(N * 16 + 255) / 256, 256, 0, stream>>>(x, xb, N * 16);
    hist_kernel<<<(E + 255) / 256, 256, 0, stream>>>(ei, deg, rank, E, N);
    scan_a_kernel<<<NB, 256, 0, stream>>>(deg, rs, bsumi, N);
    scan_b_kernel<<<1, 512, 0, stream>>>(bsumi, NB);
    scan_c_kernel<<<(N + 255) / 256, 256, 0, stream>>>(rs, bsumi, N, E);
    scatter_kernel<<<2048, 256, 0, stream>>>(ei, rs, deg, rank, srcs, E, N, inv8N);
    node_gather_kernel<<<((size_t)N * 64 + 255) / 256, 256, 0, stream>>>(x, xb, rs, srcs, msgvar, N);
    gemm_kernel<<<(N + 63) / 64, 256, 0, stream>>>(x, msgvar, Ws, bs, Wn, bn, Wv, bv, out, N);
}

// Round 8
// 278.310 us; speedup vs baseline: 1.2231x; 1.1080x over previous
//
#include <hip/hip_runtime.h>

// RAConv: reciprocal-attention graph conv, N=100K nodes, E=1.6M edges, D=64, fp32.
// Strategy: counting-sort edges by dst (CSR), then wave-per-node register
// accumulation, then fused bf16-MFMA epilogue GEMM.
//   attn normalization folded: msg = (sum_e x_src*exp(logit)) / (sum_e exp(logit))
//   var  = E[x^2] - E[x]^2   (exact rewrite of double scatter-mean)
// R2: node_gather -> split-half wave layout.
// R3: gemm -> mfma_f32_16x16x32_bf16, A=[x|msg|var] staged bf16 in LDS.
// R4: scatter XCD-partitioned for srcs write combining.
// R5: gather datapath bf16 (xb precomputed, 4 edges/wave, msgvar bf16).
// R6: float-scale partition (neutral -> atomics, not VALU, are the cost).
// R7: 8-copy rank-recording histogram; scatter made atomic-free.
// R8: gather: direct srcs[p+g] (kills 4-load+select artifact), 2-batch
//     software pipeline (indices -> rows -> compute). gemm: stage x-part from
//     xb (bf16, half fetch, no convert) + 2 node-tiles/block with W-frags
//     resident.

static inline size_t ws_align(size_t x) { return (x + 255) & ~size_t(255); }

typedef __attribute__((ext_vector_type(8))) short bf16x8;
typedef __attribute__((ext_vector_type(4))) float f32x4;

__device__ __forceinline__ unsigned short f2bf(float f) {
    unsigned u = __builtin_bit_cast(unsigned, f);
    u += 0x7FFFu + ((u >> 16) & 1u);          // RNE
    return (unsigned short)(u >> 16);
}
__device__ __forceinline__ float bfhi(int d) {          // high bf16 of dword
    return __builtin_bit_cast(float, (unsigned)d & 0xFFFF0000u);
}
__device__ __forceinline__ float bflo(int d) {          // low bf16 of dword
    return __builtin_bit_cast(float, (unsigned)d << 16);
}

__global__ void cast_kernel(const float* __restrict__ x, unsigned short* __restrict__ xb, int n4) {
    int i = blockIdx.x * blockDim.x + threadIdx.x;
    if (i < n4) {
        float4 v = ((const float4*)x)[i];
        ushort4 h; h.x = f2bf(v.x); h.y = f2bf(v.y); h.z = f2bf(v.z); h.w = f2bf(v.w);
        ((ushort4*)xb)[i] = h;
    }
}

// 8-copy histogram + rank recording. Copy c = (e>>8)&7 is wave-uniform
// and reproducible in scatter. Returned old value = rank within (copy, dst).
__global__ void __launch_bounds__(256) hist_kernel(const int* __restrict__ ei,
                                                   int* __restrict__ deg,
                                                   int* __restrict__ rank, int E, int N) {
    int e = blockIdx.x * 256 + threadIdx.x;
    if (e < E) {
        int dst = ei[E + e];
        int c = (e >> 8) & 7;
        rank[e] = atomicAdd(&deg[c * N + dst], 1);
    }
}

// Per-node: fold 8 copies -> total degree, converting copies in place to
// exclusive per-copy offsets. Then per-block exclusive scan of totals.
__global__ void scan_a_kernel(int* __restrict__ deg, int* __restrict__ rs,
                              int* __restrict__ bsum, int N) {
    __shared__ int t[256];
    int i = blockIdx.x * 256 + threadIdx.x;
    int total = 0;
    if (i < N) {
        int acc = 0;
        #pragma unroll
        for (int c = 0; c < 8; ++c) {
            int v = deg[c * N + i];
            deg[c * N + i] = acc;          // exclusive prefix across copies
            acc += v;
        }
        total = acc;
    }
    t[threadIdx.x] = total;
    __syncthreads();
    for (int off = 1; off < 256; off <<= 1) {
        int u = (threadIdx.x >= (unsigned)off) ? t[threadIdx.x - off] : 0;
        __syncthreads();
        t[threadIdx.x] += u;
        __syncthreads();
    }
    if (i < N) rs[i] = t[threadIdx.x] - total;   // exclusive within block
    if (threadIdx.x == 255) bsum[blockIdx.x] = t[255];
}

// Exclusive scan of block sums (nb <= 512).
__global__ void scan_b_kernel(int* __restrict__ bsum, int nb) {
    __shared__ int t[512];
    int i = threadIdx.x;
    int v = (i < nb) ? bsum[i] : 0;
    t[i] = v;
    __syncthreads();
    for (int off = 1; off < 512; off <<= 1) {
        int u = (i >= off) ? t[i - off] : 0;
        __syncthreads();
        t[i] += u;
        __syncthreads();
    }
    if (i < nb) bsum[i] = t[i] - v;             // exclusive
}

__global__ void scan_c_kernel(int* __restrict__ rs, const int* __restrict__ bsum,
                              int N, int E) {
    int i = blockIdx.x * blockDim.x + threadIdx.x;
    if (i < N) rs[i] += bsum[i >> 8];
    if (i == 0) rs[N] = E;
}

// Atomic-free scatter: pos = rs[dst] + copyoff[c][dst] + rank[e].
// 8-way dst-partition retained only for srcs write-combining locality.
__global__ void __launch_bounds__(256) scatter_kernel(const int* __restrict__ ei,
                                                      const int* __restrict__ rs,
                                                      const int* __restrict__ deg,
                                                      const int* __restrict__ rank,
                                                      int* __restrict__ srcs, int E, int N,
                                                      float inv8N) {
    int part = blockIdx.x & 7;
    int vb   = blockIdx.x >> 3;
    int nvb  = gridDim.x >> 3;
    const int* dstp = ei + E;
    for (int base = vb * 256; base < E; base += nvb * 256) {
        int e = base + threadIdx.x;
        if (e < E) {
            int dst = dstp[e];
            int p = min((int)((float)dst * inv8N), 7);
            if (p == part) {
                int c = (e >> 8) & 7;                  // same rule as hist
                int pos = rs[dst] + deg[c * N + dst] + rank[e];
                srcs[pos] = ei[e];
            }
        }
    }
}

// One wave per node, 4 edges per batch: 16-lane group g handles edge srcs[p+g],
// lane q=lane&15 holds features 4q..4q+3. Main loop: 2 batches pipelined
// (indices -> rows -> compute) for clean independent latency chains.
__global__ void __launch_bounds__(256) node_gather_kernel(
        const float* __restrict__ x, const unsigned short* __restrict__ xb,
        const int* __restrict__ rs, const int* __restrict__ srcs,
        unsigned short* __restrict__ msgvar, int N) {
    int w = (blockIdx.x * blockDim.x + threadIdx.x) >> 6;
    if (w >= N) return;
    int lane = threadIdx.x & 63;
    int q = lane & 15;                 // feature block (features 4q..4q+3)
    int g = lane >> 4;                 // edge slot within batch of 4
    int s = rs[w], e = rs[w + 1];
    const int2* xb2 = (const int2*)xb;            // row = 16 int2 (128 B)
    float4 xn = ((const float4*)(x + (size_t)w * 64))[q];
    float den = 0.f;
    float4 sx = {0,0,0,0}, ssq = {0,0,0,0}, sme = {0,0,0,0};

    auto compute = [&](int2 d) {
        float f0 = bflo(d.x), f1 = bfhi(d.x), f2 = bflo(d.y), f3 = bfhi(d.y);
        float t = fmaf(f0, xn.x, fmaf(f1, xn.y, fmaf(f2, xn.z, f3 * xn.w)));
        #pragma unroll
        for (int off = 1; off < 16; off <<= 1) t += __shfl_xor(t, off, 64);
        float ex = __expf(t * 0.125f);
        den += ex;
        sx.x += f0; sx.y += f1; sx.z += f2; sx.w += f3;
        ssq.x = fmaf(f0, f0, ssq.x); ssq.y = fmaf(f1, f1, ssq.y);
        ssq.z = fmaf(f2, f2, ssq.z); ssq.w = fmaf(f3, f3, ssq.w);
        sme.x = fmaf(ex, f0, sme.x); sme.y = fmaf(ex, f1, sme.y);
        sme.z = fmaf(ex, f2, sme.z); sme.w = fmaf(ex, f3, sme.w);
    };

    int p = s;
    for (; p + 8 <= e; p += 8) {                  // 2 batches, pipelined
        int ra = srcs[p + g];
        int rb = srcs[p + 4 + g];
        int2 da = xb2[(size_t)ra * 16 + q];
        int2 db = xb2[(size_t)rb * 16 + q];
        compute(da);
        compute(db);
    }
    if (p + 4 <= e) {
        int r = srcs[p + g];
        compute(xb2[(size_t)r * 16 + q]);
        p += 4;
    }
    if (p < e) {                                  // masked tail (1-3 edges)
        float wt = (p + g < e) ? 1.f : 0.f;
        int r = srcs[min(p + g, e - 1)];
        int2 d = xb2[(size_t)r * 16 + q];
        float f0 = bflo(d.x), f1 = bfhi(d.x), f2 = bflo(d.y), f3 = bfhi(d.y);
        float t = fmaf(f0, xn.x, fmaf(f1, xn.y, fmaf(f2, xn.z, f3 * xn.w)));
        #pragma unroll
        for (int off = 1; off < 16; off <<= 1) t += __shfl_xor(t, off, 64);
        float ex = __expf(t * 0.125f) * wt;
        float w0 = f0 * wt, w1 = f1 * wt, w2 = f2 * wt, w3 = f3 * wt;
        den += ex;
        sx.x += w0; sx.y += w1; sx.z += w2; sx.w += w3;
        ssq.x = fmaf(w0, f0, ssq.x); ssq.y = fmaf(w1, f1, ssq.y);
        ssq.z = fmaf(w2, f2, ssq.z); ssq.w = fmaf(w3, f3, ssq.w);
        sme.x = fmaf(ex, f0, sme.x); sme.y = fmaf(ex, f1, sme.y);
        sme.z = fmaf(ex, f2, sme.z); sme.w = fmaf(ex, f3, sme.w);
    }
    // combine the 4 groups (lanes q, q+16, q+32, q+48 hold the same features)
    #pragma unroll
    for (int off = 16; off < 64; off <<= 1) {
        den   += __shfl_xor(den,   off, 64);
        sx.x  += __shfl_xor(sx.x,  off, 64); sx.y  += __shfl_xor(sx.y,  off, 64);
        sx.z  += __shfl_xor(sx.z,  off, 64); sx.w  += __shfl_xor(sx.w,  off, 64);
        ssq.x += __shfl_xor(ssq.x, off, 64); ssq.y += __shfl_xor(ssq.y, off, 64);
        ssq.z += __shfl_xor(ssq.z, off, 64); ssq.w += __shfl_xor(ssq.w, off, 64);
        sme.x += __shfl_xor(sme.x, off, 64); sme.y += __shfl_xor(sme.y, off, 64);
        sme.z += __shfl_xor(sme.z, off, 64); sme.w += __shfl_xor(sme.w, off, 64);
    }
    if (lane < 16) {
        float inv = 1.f / fmaxf((float)(e - s), 1.f);
        float invden = (den > 0.f) ? (1.f / den) : 0.f;
        float mx = sx.x * inv, my = sx.y * inv, mz = sx.z * inv, mw = sx.w * inv;
        ushort4 hm, hv;
        hm.x = f2bf(sme.x * invden); hm.y = f2bf(sme.y * invden);
        hm.z = f2bf(sme.z * invden); hm.w = f2bf(sme.w * invden);
        hv.x = f2bf(ssq.x * inv - mx * mx); hv.y = f2bf(ssq.y * inv - my * my);
        hv.z = f2bf(ssq.z * inv - mz * mz); hv.w = f2bf(ssq.w * inv - mw * mw);
        *(ushort4*)&msgvar[(size_t)w * 128 + 4 * q]      = hm;
        *(ushort4*)&msgvar[(size_t)w * 128 + 64 + 4 * q] = hv;
    }
}

// MFMA epilogue GEMM: out = A @ Wcat^T + b, A = [x | msg | var] (N x 192),
// all inputs already bf16 (xb, msgvar). 2 node-tiles of 64 per block with
// W-fragments and bias resident in registers across tiles.
__global__ void __launch_bounds__(256) gemm_kernel(
        const unsigned short* __restrict__ xb, const unsigned short* __restrict__ msgvar,
        const float* __restrict__ Ws, const float* __restrict__ bs,
        const float* __restrict__ Wn, const float* __restrict__ bn,
        const float* __restrict__ Wv, const float* __restrict__ bv,
        float* __restrict__ out, int N) {
    __shared__ unsigned short As[64 * 200];
    int tid = threadIdx.x;
    int lane = tid & 63;
    int wv = tid >> 6;                  // feature tile (wave id)
    int j = lane & 15, quad = lane >> 4;
    int jg = wv * 16 + j;               // global output feature

    // B fragments: 6 K-steps, lane holds W[jg][k0..k0+7] as bf16
    const float* Wm0[3] = {Ws, Wn, Wv};
    bf16x8 bfrag[6];
    #pragma unroll
    for (int ks = 0; ks < 6; ++ks) {
        const float* W = Wm0[ks >> 1];
        int k0 = (ks & 1) * 32 + quad * 8;
        const float4* p = (const float4*)(W + (size_t)jg * 64 + k0);
        float4 a = p[0], b = p[1];
        bf16x8 f;
        f[0] = (short)f2bf(a.x); f[1] = (short)f2bf(a.y);
        f[2] = (short)f2bf(a.z); f[3] = (short)f2bf(a.w);
        f[4] = (short)f2bf(b.x); f[5] = (short)f2bf(b.y);
        f[6] = (short)f2bf(b.z); f[7] = (short)f2bf(b.w);
        bfrag[ks] = f;
    }
    float bias = bs[jg] + bn[jg] + bv[jg];

    #pragma unroll
    for (int t = 0; t < 2; ++t) {
        int nbase = blockIdx.x * 128 + t * 64;
        // stage x part from xb: 64 rows x 16 ushort4 (bf16 direct copy)
        #pragma unroll
        for (int i = 0; i < 4; ++i) {
            int idx = i * 256 + tid;
            int row = idx >> 4, c = idx & 15;
            int n = min(nbase + row, N - 1);
            ushort4 h = ((const ushort4*)(xb + (size_t)n * 64))[c];
            *(ushort4*)&As[row * 200 + c * 4] = h;
        }
        // stage msgvar part: 64 rows x 32 ushort4 (bf16, [msg|var] contiguous)
        #pragma unroll
        for (int i = 0; i < 8; ++i) {
            int idx = i * 256 + tid;
            int row = idx >> 5, c = idx & 31;
            int n = min(nbase + row, N - 1);
            ushort4 h = ((const ushort4*)(msgvar + (size_t)n * 128))[c];
            *(ushort4*)&As[row * 200 + 64 + c * 4] = h;
        }
        __syncthreads();

        f32x4 acc[4];
        #pragma unroll
        for (int nt = 0; nt < 4; ++nt) {
            acc[nt][0] = bias; acc[nt][1] = bias; acc[nt][2] = bias; acc[nt][3] = bias;
        }
        #pragma unroll
        for (int nt = 0; nt < 4; ++nt) {
            #pragma unroll
            for (int ks = 0; ks < 6; ++ks) {
                const bf16x8* ap = (const bf16x8*)&As[(nt * 16 + j) * 200 + ks * 32 + quad * 8];
                acc[nt] = __builtin_amdgcn_mfma_f32_16x16x32_bf16(*ap, bfrag[ks], acc[nt], 0, 0, 0);
            }
        }
        // D: node = nbase + nt*16 + quad*4 + r, col = jg
        #pragma unroll
        for (int nt = 0; nt < 4; ++nt) {
            #pragma unroll
            for (int r = 0; r < 4; ++r) {
                int node = nbase + nt * 16 + quad * 4 + r;
                if (node < N) out[(size_t)node * 64 + jg] = acc[nt][r];
            }
        }
        __syncthreads();   // protect As before next tile's staging
    }
}

extern "C" void kernel_launch(void* const* d_in, const int* in_sizes, int n_in,
                              void* d_out, int out_size, void* d_ws, size_t ws_size,
                              hipStream_t stream) {
    const float* x  = (const float*)d_in[0];
    const int*   ei = (const int*)d_in[1];
    const float* Ws = (const float*)d_in[2];
    const float* bs = (const float*)d_in[3];
    const float* Wn = (const float*)d_in[4];
    const float* bn = (const float*)d_in[5];
    const float* Wv = (const float*)d_in[6];
    const float* bv = (const float*)d_in[7];
    float* out = (float*)d_out;

    int N  = in_sizes[0] / 64;
    int E  = in_sizes[1] / 2;
    int NB = (N + 255) / 256;
    float inv8N = (float)(8.0 / (double)N);

    char* wsp = (char*)d_ws;
    size_t off = 0;
    int* deg    = (int*)(wsp + off); off += ws_align((size_t)N * 8 * 4);   // 8 copies
    int* rs     = (int*)(wsp + off); off += ws_align((size_t)(N + 1) * 4);
    int* bsumi  = (int*)(wsp + off); off += ws_align((size_t)NB * 4);
    int* srcs   = (int*)(wsp + off); off += ws_align((size_t)E * 4);
    int* rank   = (int*)(wsp + off); off += ws_align((size_t)E * 4);
    unsigned short* msgvar = (unsigned short*)(wsp + off); off += ws_align((size_t)N * 128 * 2);
    unsigned short* xb     = (unsigned short*)(wsp + off); off += ws_align((size_t)N * 64 * 2);

    hipMemsetAsync(deg, 0, (size_t)N * 8 * 4, stream);
    cast_kernel<<<(N * 16 + 255) / 256, 256, 0, stream>>>(x, xb, N * 16);
    hist_kernel<<<(E + 255) / 256, 256, 0, stream>>>(ei, deg, rank, E, N);
    scan_a_kernel<<<NB, 256, 0, stream>>>(deg, rs, bsumi, N);
    scan_b_kernel<<<1, 512, 0, stream>>>(bsumi, NB);
    scan_c_kernel<<<(N + 255) / 256, 256, 0, stream>>>(rs, bsumi, N, E);
    scatter_kernel<<<2048, 256, 0, stream>>>(ei, rs, deg, rank, srcs, E, N, inv8N);
    node_gather_kernel<<<((size_t)N * 64 + 255) / 256, 256, 0, stream>>>(x, xb, rs, srcs, msgvar, N);
    gemm_kernel<<<(N + 127) / 128, 256, 0, stream>>>(xb, msgvar, Ws, bs, Wn, bn, Wv, bv, out, N);
}

// Round 9
// 272.890 us; speedup vs baseline: 1.2474x; 1.0199x over previous
//
#include <hip/hip_runtime.h>

// RAConv: reciprocal-attention graph conv, N=100K nodes, E=1.6M edges, D=64, fp32.
// CSR counting-sort by dst -> wave-per-node register gather -> bf16 MFMA GEMM.
//   msg = (sum_e x_src*exp(logit)) / (sum_e exp(logit));  var = E[x^2]-E[x]^2
// R2-R8: see git log (split-half gather, MFMA gemm, XCD partition, bf16
//        datapath, rank-recording hist, atomic-free scatter, pipelined loads).
// R9: gather accum/dot packed as float2 (targets v_pk_fma_f32 on gfx950;
//     neutral if scalarized). scatter 8->4 partitions (halves the redundant
//     51+51 MB stream re-reads; write locality now per XCD-pair). deg memset
//     folded into cast_kernel (one fewer launch).

static inline size_t ws_align(size_t x) { return (x + 255) & ~size_t(255); }

typedef __attribute__((ext_vector_type(8))) short bf16x8;
typedef __attribute__((ext_vector_type(4))) float f32x4;
typedef __attribute__((ext_vector_type(2))) float f32x2;

__device__ __forceinline__ unsigned short f2bf(float f) {
    unsigned u = __builtin_bit_cast(unsigned, f);
    u += 0x7FFFu + ((u >> 16) & 1u);          // RNE
    return (unsigned short)(u >> 16);
}
__device__ __forceinline__ float bfhi(int d) {          // high bf16 of dword
    return __builtin_bit_cast(float, (unsigned)d & 0xFFFF0000u);
}
__device__ __forceinline__ float bflo(int d) {          // low bf16 of dword
    return __builtin_bit_cast(float, (unsigned)d << 16);
}

// cast x -> bf16 AND zero the 8-copy deg array (folded memset).
__global__ void cast_kernel(const float* __restrict__ x, unsigned short* __restrict__ xb,
                            int* __restrict__ deg, int n4, int ndeg4) {
    int i = blockIdx.x * blockDim.x + threadIdx.x;
    if (i < n4) {
        float4 v = ((const float4*)x)[i];
        ushort4 h; h.x = f2bf(v.x); h.y = f2bf(v.y); h.z = f2bf(v.z); h.w = f2bf(v.w);
        ((ushort4*)xb)[i] = h;
    }
    if (i < ndeg4) {
        int4 z = {0, 0, 0, 0};
        ((int4*)deg)[i] = z;
    }
}

// 8-copy histogram + rank recording. Copy c = (e>>8)&7 is wave-uniform
// and reproducible in scatter. Returned old value = rank within (copy, dst).
__global__ void __launch_bounds__(256) hist_kernel(const int* __restrict__ ei,
                                                   int* __restrict__ deg,
                                                   int* __restrict__ rank, int E, int N) {
    int e = blockIdx.x * 256 + threadIdx.x;
    if (e < E) {
        int dst = ei[E + e];
        int c = (e >> 8) & 7;
        rank[e] = atomicAdd(&deg[c * N + dst], 1);
    }
}

// Per-node: fold 8 copies -> total degree, converting copies in place to
// exclusive per-copy offsets. Then per-block exclusive scan of totals.
__global__ void scan_a_kernel(int* __restrict__ deg, int* __restrict__ rs,
                              int* __restrict__ bsum, int N) {
    __shared__ int t[256];
    int i = blockIdx.x * 256 + threadIdx.x;
    int total = 0;
    if (i < N) {
        int acc = 0;
        #pragma unroll
        for (int c = 0; c < 8; ++c) {
            int v = deg[c * N + i];
            deg[c * N + i] = acc;          // exclusive prefix across copies
            acc += v;
        }
        total = acc;
    }
    t[threadIdx.x] = total;
    __syncthreads();
    for (int off = 1; off < 256; off <<= 1) {
        int u = (threadIdx.x >= (unsigned)off) ? t[threadIdx.x - off] : 0;
        __syncthreads();
        t[threadIdx.x] += u;
        __syncthreads();
    }
    if (i < N) rs[i] = t[threadIdx.x] - total;   // exclusive within block
    if (threadIdx.x == 255) bsum[blockIdx.x] = t[255];
}

// Exclusive scan of block sums (nb <= 512).
__global__ void scan_b_kernel(int* __restrict__ bsum, int nb) {
    __shared__ int t[512];
    int i = threadIdx.x;
    int v = (i < nb) ? bsum[i] : 0;
    t[i] = v;
    __syncthreads();
    for (int off = 1; off < 512; off <<= 1) {
        int u = (i >= off) ? t[i - off] : 0;
        __syncthreads();
        t[i] += u;
        __syncthreads();
    }
    if (i < nb) bsum[i] = t[i] - v;             // exclusive
}

__global__ void scan_c_kernel(int* __restrict__ rs, const int* __restrict__ bsum,
                              int N, int E) {
    int i = blockIdx.x * blockDim.x + threadIdx.x;
    if (i < N) rs[i] += bsum[i >> 8];
    if (i == 0) rs[N] = E;
}

// Atomic-free scatter: pos = rs[dst] + copyoff[c][dst] + rank[e].
// 4-way dst-partition (XCD pairs): halves redundant stream reads vs 8-way
// while keeping most write-combining locality.
__global__ void __launch_bounds__(256) scatter_kernel(const int* __restrict__ ei,
                                                      const int* __restrict__ rs,
                                                      const int* __restrict__ deg,
                                                      const int* __restrict__ rank,
                                                      int* __restrict__ srcs, int E, int N,
                                                      float inv4N) {
    int part = blockIdx.x & 3;
    int vb   = blockIdx.x >> 2;
    int nvb  = gridDim.x >> 2;
    const int* dstp = ei + E;
    for (int base = vb * 256; base < E; base += nvb * 256) {
        int e = base + threadIdx.x;
        if (e < E) {
            int dst = dstp[e];
            int p = min((int)((float)dst * inv4N), 3);
            if (p == part) {
                int c = (e >> 8) & 7;                  // same rule as hist
                int pos = rs[dst] + deg[c * N + dst] + rank[e];
                srcs[pos] = ei[e];
            }
        }
    }
}

// One wave per node, 4 edges per batch: 16-lane group g handles edge srcs[p+g],
// lane q=lane&15 holds features 4q..4q+3 as two float2 (packed-fp32 ALU path).
__global__ void __launch_bounds__(256) node_gather_kernel(
        const float* __restrict__ x, const unsigned short* __restrict__ xb,
        const int* __restrict__ rs, const int* __restrict__ srcs,
        unsigned short* __restrict__ msgvar, int N) {
    int w = (blockIdx.x * blockDim.x + threadIdx.x) >> 6;
    if (w >= N) return;
    int lane = threadIdx.x & 63;
    int q = lane & 15;                 // feature block (features 4q..4q+3)
    int g = lane >> 4;                 // edge slot within batch of 4
    int s = rs[w], e = rs[w + 1];
    const int2* xb2 = (const int2*)xb;            // row = 16 int2 (128 B)
    float4 xn = ((const float4*)(x + (size_t)w * 64))[q];
    f32x2 xn01 = {xn.x, xn.y}, xn23 = {xn.z, xn.w};
    float den = 0.f;
    f32x2 sxa = {0,0}, sxb = {0,0}, ssqa = {0,0}, ssqb = {0,0},
          smea = {0,0}, smeb = {0,0};

    auto compute = [&](int2 d) {
        f32x2 a = {bflo(d.x), bfhi(d.x)};
        f32x2 b = {bflo(d.y), bfhi(d.y)};
        f32x2 dp = a * xn01 + b * xn23;           // pk mul + pk fma
        float t = dp.x + dp.y;
        #pragma unroll
        for (int off = 1; off < 16; off <<= 1) t += __shfl_xor(t, off, 64);
        float ex = __expf(t * 0.125f);
        f32x2 ex2 = {ex, ex};
        den += ex;
        sxa += a;           sxb += b;             // pk add
        ssqa += a * a;      ssqb += b * b;        // pk fma
        smea += ex2 * a;    smeb += ex2 * b;      // pk fma
    };

    int p = s;
    for (; p + 8 <= e; p += 8) {                  // 2 batches, pipelined
        int ra = srcs[p + g];
        int rb = srcs[p + 4 + g];
        int2 da = xb2[(size_t)ra * 16 + q];
        int2 db = xb2[(size_t)rb * 16 + q];
        compute(da);
        compute(db);
    }
    if (p + 4 <= e) {
        int r = srcs[p + g];
        compute(xb2[(size_t)r * 16 + q]);
        p += 4;
    }
    if (p < e) {                                  // masked tail (1-3 edges)
        float wt = (p + g < e) ? 1.f : 0.f;
        int r = srcs[min(p + g, e - 1)];
        int2 d = xb2[(size_t)r * 16 + q];
        f32x2 a = {bflo(d.x), bfhi(d.x)};
        f32x2 b = {bflo(d.y), bfhi(d.y)};
        f32x2 dp = a * xn01 + b * xn23;
        float t = dp.x + dp.y;
        #pragma unroll
        for (int off = 1; off < 16; off <<= 1) t += __shfl_xor(t, off, 64);
        float ex = __expf(t * 0.125f) * wt;
        f32x2 wt2 = {wt, wt}, ex2 = {ex, ex};
        f32x2 wa = a * wt2, wb = b * wt2;
        den += ex;
        sxa += wa;          sxb += wb;
        ssqa += wa * a;     ssqb += wb * b;
        smea += ex2 * a;    smeb += ex2 * b;
    }
    // combine the 4 groups (lanes q, q+16, q+32, q+48 hold the same features)
    #pragma unroll
    for (int off = 16; off < 64; off <<= 1) {
        den    += __shfl_xor(den,    off, 64);
        sxa.x  += __shfl_xor(sxa.x,  off, 64); sxa.y  += __shfl_xor(sxa.y,  off, 64);
        sxb.x  += __shfl_xor(sxb.x,  off, 64); sxb.y  += __shfl_xor(sxb.y,  off, 64);
        ssqa.x += __shfl_xor(ssqa.x, off, 64); ssqa.y += __shfl_xor(ssqa.y, off, 64);
        ssqb.x += __shfl_xor(ssqb.x, off, 64); ssqb.y += __shfl_xor(ssqb.y, off, 64);
        smea.x += __shfl_xor(smea.x, off, 64); smea.y += __shfl_xor(smea.y, off, 64);
        smeb.x += __shfl_xor(smeb.x, off, 64); smeb.y += __shfl_xor(smeb.y, off, 64);
    }
    if (lane < 16) {
        float inv = 1.f / fmaxf((float)(e - s), 1.f);
        float invden = (den > 0.f) ? (1.f / den) : 0.f;
        float m0 = sxa.x * inv, m1 = sxa.y * inv, m2 = sxb.x * inv, m3 = sxb.y * inv;
        ushort4 hm, hv;
        hm.x = f2bf(smea.x * invden); hm.y = f2bf(smea.y * invden);
        hm.z = f2bf(smeb.x * invden); hm.w = f2bf(smeb.y * invden);
        hv.x = f2bf(ssqa.x * inv - m0 * m0); hv.y = f2bf(ssqa.y * inv - m1 * m1);
        hv.z = f2bf(ssqb.x * inv - m2 * m2); hv.w = f2bf(ssqb.y * inv - m3 * m3);
        *(ushort4*)&msgvar[(size_t)w * 128 + 4 * q]      = hm;
        *(ushort4*)&msgvar[(size_t)w * 128 + 64 + 4 * q] = hv;
    }
}

// MFMA epilogue GEMM: out = A @ Wcat^T + b, A = [x | msg | var] (N x 192),
// all inputs already bf16 (xb, msgvar). 2 node-tiles of 64 per block with
// W-fragments and bias resident in registers across tiles.
__global__ void __launch_bounds__(256) gemm_kernel(
        const unsigned short* __restrict__ xb, const unsigned short* __restrict__ msgvar,
        const float* __restrict__ Ws, const float* __restrict__ bs,
        const float* __restrict__ Wn, const float* __restrict__ bn,
        const float* __restrict__ Wv, const float* __restrict__ bv,
        float* __restrict__ out, int N) {
    __shared__ unsigned short As[64 * 200];
    int tid = threadIdx.x;
    int lane = tid & 63;
    int wv = tid >> 6;                  // feature tile (wave id)
    int j = lane & 15, quad = lane >> 4;
    int jg = wv * 16 + j;               // global output feature

    // B fragments: 6 K-steps, lane holds W[jg][k0..k0+7] as bf16
    const float* Wm0[3] = {Ws, Wn, Wv};
    bf16x8 bfrag[6];
    #pragma unroll
    for (int ks = 0; ks < 6; ++ks) {
        const float* W = Wm0[ks >> 1];
        int k0 = (ks & 1) * 32 + quad * 8;
        const float4* p = (const float4*)(W + (size_t)jg * 64 + k0);
        float4 a = p[0], b = p[1];
        bf16x8 f;
        f[0] = (short)f2bf(a.x); f[1] = (short)f2bf(a.y);
        f[2] = (short)f2bf(a.z); f[3] = (short)f2bf(a.w);
        f[4] = (short)f2bf(b.x); f[5] = (short)f2bf(b.y);
        f[6] = (short)f2bf(b.z); f[7] = (short)f2bf(b.w);
        bfrag[ks] = f;
    }
    float bias = bs[jg] + bn[jg] + bv[jg];

    #pragma unroll
    for (int t = 0; t < 2; ++t) {
        int nbase = blockIdx.x * 128 + t * 64;
        // stage x part from xb: 64 rows x 16 ushort4 (bf16 direct copy)
        #pragma unroll
        for (int i = 0; i < 4; ++i) {
            int idx = i * 256 + tid;
            int row = idx >> 4, c = idx & 15;
            int n = min(nbase + row, N - 1);
            ushort4 h = ((const ushort4*)(xb + (size_t)n * 64))[c];
            *(ushort4*)&As[row * 200 + c * 4] = h;
        }
        // stage msgvar part: 64 rows x 32 ushort4 (bf16, [msg|var] contiguous)
        #pragma unroll
        for (int i = 0; i < 8; ++i) {
            int idx = i * 256 + tid;
            int row = idx >> 5, c = idx & 31;
            int n = min(nbase + row, N - 1);
            ushort4 h = ((const ushort4*)(msgvar + (size_t)n * 128))[c];
            *(ushort4*)&As[row * 200 + 64 + c * 4] = h;
        }
        __syncthreads();

        f32x4 acc[4];
        #pragma unroll
        for (int nt = 0; nt < 4; ++nt) {
            acc[nt][0] = bias; acc[nt][1] = bias; acc[nt][2] = bias; acc[nt][3] = bias;
        }
        #pragma unroll
        for (int nt = 0; nt < 4; ++nt) {
            #pragma unroll
            for (int ks = 0; ks < 6; ++ks) {
                const bf16x8* ap = (const bf16x8*)&As[(nt * 16 + j) * 200 + ks * 32 + quad * 8];
                acc[nt] = __builtin_amdgcn_mfma_f32_16x16x32_bf16(*ap, bfrag[ks], acc[nt], 0, 0, 0);
            }
        }
        // D: node = nbase + nt*16 + quad*4 + r, col = jg
        #pragma unroll
        for (int nt = 0; nt < 4; ++nt) {
            #pragma unroll
            for (int r = 0; r < 4; ++r) {
                int node = nbase + nt * 16 + quad * 4 + r;
                if (node < N) out[(size_t)node * 64 + jg] = acc[nt][r];
            }
        }
        __syncthreads();   // protect As before next tile's staging
    }
}

extern "C" void kernel_launch(void* const* d_in, const int* in_sizes, int n_in,
                              void* d_out, int out_size, void* d_ws, size_t ws_size,
                              hipStream_t stream) {
    const float* x  = (const float*)d_in[0];
    const int*   ei = (const int*)d_in[1];
    const float* Ws = (const float*)d_in[2];
    const float* bs = (const float*)d_in[3];
    const float* Wn = (const float*)d_in[4];
    const float* bn = (const float*)d_in[5];
    const float* Wv = (const float*)d_in[6];
    const float* bv = (const float*)d_in[7];
    float* out = (float*)d_out;

    int N  = in_sizes[0] / 64;
    int E  = in_sizes[1] / 2;
    int NB = (N + 255) / 256;
    float inv4N = (float)(4.0 / (double)N);

    char* wsp = (char*)d_ws;
    size_t off = 0;
    int* deg    = (int*)(wsp + off); off += ws_align((size_t)N * 8 * 4);   // 8 copies
    int* rs     = (int*)(wsp + off); off += ws_align((size_t)(N + 1) * 4);
    int* bsumi  = (int*)(wsp + off); off += ws_align((size_t)NB * 4);
    int* srcs   = (int*)(wsp + off); off += ws_align((size_t)E * 4);
    int* rank   = (int*)(wsp + off); off += ws_align((size_t)E * 4);
    unsigned short* msgvar = (unsigned short*)(wsp + off); off += ws_align((size_t)N * 128 * 2);
    unsigned short* xb     = (unsigned short*)(wsp + off); off += ws_align((size_t)N * 64 * 2);

    int n4 = N * 16, ndeg4 = N * 2;
    cast_kernel<<<(max(n4, ndeg4) + 255) / 256, 256, 0, stream>>>(x, xb, deg, n4, ndeg4);
    hist_kernel<<<(E + 255) / 256, 256, 0, stream>>>(ei, deg, rank, E, N);
    scan_a_kernel<<<NB, 256, 0, stream>>>(deg, rs, bsumi, N);
    scan_b_kernel<<<1, 512, 0, stream>>>(bsumi, NB);
    scan_c_kernel<<<(N + 255) / 256, 256, 0, stream>>>(rs, bsumi, N, E);
    scatter_kernel<<<2048, 256, 0, stream>>>(ei, rs, deg, rank, srcs, E, N, inv4N);
    node_gather_kernel<<<((size_t)N * 64 + 255) / 256, 256, 0, stream>>>(x, xb, rs, srcs, msgvar, N);
    gemm_kernel<<<(N + 127) / 128, 256, 0, stream>>>(xb, msgvar, Ws, bs, Wn, bn, Wv, bv, out, N);
}

// Round 10
// 267.010 us; speedup vs baseline: 1.2748x; 1.0220x over previous
//
#include <hip/hip_runtime.h>

// RAConv: reciprocal-attention graph conv, N=100K nodes, E=1.6M edges, D=64, fp32.
// CSR counting-sort by dst -> wave-per-node register gather -> bf16 MFMA GEMM.
//   msg = (sum_e x_src*exp(logit)) / (sum_e exp(logit));  var = E[x^2]-E[x]^2
// R2-R9: see git log (split-half gather, MFMA gemm, XCD partition, bf16
//        datapath, rank-recording hist, atomic-free scatter, pipelined loads,
//        pk-fp32 accum, 4-way scatter partitions).
// R10: cast fused into hist (x->bf16 stream hides under atomic latency);
//      scan_c folds rs into copy-offsets -> scatter does ONE random read
//      (base[c][dst]+rank[e]); gather reads xn from xb (bf16 logit, -12.8MB).

static inline size_t ws_align(size_t x) { return (x + 255) & ~size_t(255); }

typedef __attribute__((ext_vector_type(8))) short bf16x8;
typedef __attribute__((ext_vector_type(4))) float f32x4;
typedef __attribute__((ext_vector_type(2))) float f32x2;

__device__ __forceinline__ unsigned short f2bf(float f) {
    unsigned u = __builtin_bit_cast(unsigned, f);
    u += 0x7FFFu + ((u >> 16) & 1u);          // RNE
    return (unsigned short)(u >> 16);
}
__device__ __forceinline__ float bfhi(int d) {          // high bf16 of dword
    return __builtin_bit_cast(float, (unsigned)d & 0xFFFF0000u);
}
__device__ __forceinline__ float bflo(int d) {          // low bf16 of dword
    return __builtin_bit_cast(float, (unsigned)d << 16);
}

// Fused: cast x->bf16 (i < n4) AND 8-copy histogram + rank recording (e < E).
// Copy c = (e>>8)&7 is wave-uniform and reproducible in scatter. deg must be
// pre-zeroed (hipMemsetAsync).
__global__ void __launch_bounds__(256) hist_cast_kernel(
        const float* __restrict__ x, unsigned short* __restrict__ xb,
        const int* __restrict__ ei, int* __restrict__ deg,
        int* __restrict__ rank, int E, int N, int n4) {
    int i = blockIdx.x * 256 + threadIdx.x;
    if (i < n4) {
        float4 v = ((const float4*)x)[i];
        ushort4 h; h.x = f2bf(v.x); h.y = f2bf(v.y); h.z = f2bf(v.z); h.w = f2bf(v.w);
        ((ushort4*)xb)[i] = h;
    }
    if (i < E) {
        int dst = ei[E + i];
        int c = (i >> 8) & 7;
        rank[i] = atomicAdd(&deg[c * N + dst], 1);
    }
}

// Per-node: fold 8 copies -> total degree, converting copies in place to
// exclusive per-copy offsets. Then per-block exclusive scan of totals.
__global__ void scan_a_kernel(int* __restrict__ deg, int* __restrict__ rs,
                              int* __restrict__ bsum, int N) {
    __shared__ int t[256];
    int i = blockIdx.x * 256 + threadIdx.x;
    int total = 0;
    if (i < N) {
        int acc = 0;
        #pragma unroll
        for (int c = 0; c < 8; ++c) {
            int v = deg[c * N + i];
            deg[c * N + i] = acc;          // exclusive prefix across copies
            acc += v;
        }
        total = acc;
    }
    t[threadIdx.x] = total;
    __syncthreads();
    for (int off = 1; off < 256; off <<= 1) {
        int u = (threadIdx.x >= (unsigned)off) ? t[threadIdx.x - off] : 0;
        __syncthreads();
        t[threadIdx.x] += u;
        __syncthreads();
    }
    if (i < N) rs[i] = t[threadIdx.x] - total;   // exclusive within block
    if (threadIdx.x == 255) bsum[blockIdx.x] = t[255];
}

// Exclusive scan of block sums (nb <= 512).
__global__ void scan_b_kernel(int* __restrict__ bsum, int nb) {
    __shared__ int t[512];
    int i = threadIdx.x;
    int v = (i < nb) ? bsum[i] : 0;
    t[i] = v;
    __syncthreads();
    for (int off = 1; off < 512; off <<= 1) {
        int u = (i >= off) ? t[i - off] : 0;
        __syncthreads();
        t[i] += u;
        __syncthreads();
    }
    if (i < nb) bsum[i] = t[i] - v;             // exclusive
}

// Finalize rs AND fold it into the copy-offsets: deg[c][i] += rs[i], so that
// scatter needs a single random read (base[c][dst] + rank[e]).
__global__ void scan_c_kernel(int* __restrict__ rs, const int* __restrict__ bsum,
                              int* __restrict__ deg, int N, int E) {
    int i = blockIdx.x * blockDim.x + threadIdx.x;
    if (i < N) {
        int r = rs[i] + bsum[i >> 8];
        rs[i] = r;
        #pragma unroll
        for (int c = 0; c < 8; ++c) deg[c * N + i] += r;
    }
    if (i == 0) rs[N] = E;
}

// Atomic-free scatter: pos = base[c][dst] + rank[e] (one random read).
// 4-way dst-partition (XCD pairs) for srcs write-combining locality.
__global__ void __launch_bounds__(256) scatter_kernel(const int* __restrict__ ei,
                                                      const int* __restrict__ base,
                                                      const int* __restrict__ rank,
                                                      int* __restrict__ srcs, int E, int N,
                                                      float inv4N) {
    int part = blockIdx.x & 3;
    int vb   = blockIdx.x >> 2;
    int nvb  = gridDim.x >> 2;
    const int* dstp = ei + E;
    for (int bbase = vb * 256; bbase < E; bbase += nvb * 256) {
        int e = bbase + threadIdx.x;
        if (e < E) {
            int dst = dstp[e];
            int p = min((int)((float)dst * inv4N), 3);
            if (p == part) {
                int c = (e >> 8) & 7;                  // same rule as hist
                int pos = base[c * N + dst] + rank[e];
                srcs[pos] = ei[e];
            }
        }
    }
}

// One wave per node, 4 edges per batch: 16-lane group g handles edge srcs[p+g],
// lane q=lane&15 holds features 4q..4q+3 as two float2 (packed-fp32 ALU path).
// xn now read from xb (bf16): logit is bf16*bf16 -> fp32.
__global__ void __launch_bounds__(256) node_gather_kernel(
        const unsigned short* __restrict__ xb,
        const int* __restrict__ rs, const int* __restrict__ srcs,
        unsigned short* __restrict__ msgvar, int N) {
    int w = (blockIdx.x * blockDim.x + threadIdx.x) >> 6;
    if (w >= N) return;
    int lane = threadIdx.x & 63;
    int q = lane & 15;                 // feature block (features 4q..4q+3)
    int g = lane >> 4;                 // edge slot within batch of 4
    int s = rs[w], e = rs[w + 1];
    const int2* xb2 = (const int2*)xb;            // row = 16 int2 (128 B)
    int2 dn = xb2[(size_t)w * 16 + q];
    f32x2 xn01 = {bflo(dn.x), bfhi(dn.x)}, xn23 = {bflo(dn.y), bfhi(dn.y)};
    float den = 0.f;
    f32x2 sxa = {0,0}, sxb = {0,0}, ssqa = {0,0}, ssqb = {0,0},
          smea = {0,0}, smeb = {0,0};

    auto compute = [&](int2 d) {
        f32x2 a = {bflo(d.x), bfhi(d.x)};
        f32x2 b = {bflo(d.y), bfhi(d.y)};
        f32x2 dp = a * xn01 + b * xn23;           // pk mul + pk fma
        float t = dp.x + dp.y;
        #pragma unroll
        for (int off = 1; off < 16; off <<= 1) t += __shfl_xor(t, off, 64);
        float ex = __expf(t * 0.125f);
        f32x2 ex2 = {ex, ex};
        den += ex;
        sxa += a;           sxb += b;             // pk add
        ssqa += a * a;      ssqb += b * b;        // pk fma
        smea += ex2 * a;    smeb += ex2 * b;      // pk fma
    };

    int p = s;
    for (; p + 8 <= e; p += 8) {                  // 2 batches, pipelined
        int ra = srcs[p + g];
        int rb = srcs[p + 4 + g];
        int2 da = xb2[(size_t)ra * 16 + q];
        int2 db = xb2[(size_t)rb * 16 + q];
        compute(da);
        compute(db);
    }
    if (p + 4 <= e) {
        int r = srcs[p + g];
        compute(xb2[(size_t)r * 16 + q]);
        p += 4;
    }
    if (p < e) {                                  // masked tail (1-3 edges)
        float wt = (p + g < e) ? 1.f : 0.f;
        int r = srcs[min(p + g, e - 1)];
        int2 d = xb2[(size_t)r * 16 + q];
        f32x2 a = {bflo(d.x), bfhi(d.x)};
        f32x2 b = {bflo(d.y), bfhi(d.y)};
        f32x2 dp = a * xn01 + b * xn23;
        float t = dp.x + dp.y;
        #pragma unroll
        for (int off = 1; off < 16; off <<= 1) t += __shfl_xor(t, off, 64);
        float ex = __expf(t * 0.125f) * wt;
        f32x2 wt2 = {wt, wt}, ex2 = {ex, ex};
        f32x2 wa = a * wt2, wb = b * wt2;
        den += ex;
        sxa += wa;          sxb += wb;
        ssqa += wa * a;     ssqb += wb * b;
        smea += ex2 * a;    smeb += ex2 * b;
    }
    // combine the 4 groups (lanes q, q+16, q+32, q+48 hold the same features)
    #pragma unroll
    for (int off = 16; off < 64; off <<= 1) {
        den    += __shfl_xor(den,    off, 64);
        sxa.x  += __shfl_xor(sxa.x,  off, 64); sxa.y  += __shfl_xor(sxa.y,  off, 64);
        sxb.x  += __shfl_xor(sxb.x,  off, 64); sxb.y  += __shfl_xor(sxb.y,  off, 64);
        ssqa.x += __shfl_xor(ssqa.x, off, 64); ssqa.y += __shfl_xor(ssqa.y, off, 64);
        ssqb.x += __shfl_xor(ssqb.x, off, 64); ssqb.y += __shfl_xor(ssqb.y, off, 64);
        smea.x += __shfl_xor(smea.x, off, 64); smea.y += __shfl_xor(smea.y, off, 64);
        smeb.x += __shfl_xor(smeb.x, off, 64); smeb.y += __shfl_xor(smeb.y, off, 64);
    }
    if (lane < 16) {
        float inv = 1.f / fmaxf((float)(e - s), 1.f);
        float invden = (den > 0.f) ? (1.f / den) : 0.f;
        float m0 = sxa.x * inv, m1 = sxa.y * inv, m2 = sxb.x * inv, m3 = sxb.y * inv;
        ushort4 hm, hv;
        hm.x = f2bf(smea.x * invden); hm.y = f2bf(smea.y * invden);
        hm.z = f2bf(smeb.x * invden); hm.w = f2bf(smeb.y * invden);
        hv.x = f2bf(ssqa.x * inv - m0 * m0); hv.y = f2bf(ssqa.y * inv - m1 * m1);
        hv.z = f2bf(ssqb.x * inv - m2 * m2); hv.w = f2bf(ssqb.y * inv - m3 * m3);
        *(ushort4*)&msgvar[(size_t)w * 128 + 4 * q]      = hm;
        *(ushort4*)&msgvar[(size_t)w * 128 + 64 + 4 * q] = hv;
    }
}

// MFMA epilogue GEMM: out = A @ Wcat^T + b, A = [x | msg | var] (N x 192),
// all inputs already bf16 (xb, msgvar). 2 node-tiles of 64 per block with
// W-fragments and bias resident in registers across tiles.
__global__ void __launch_bounds__(256) gemm_kernel(
        const unsigned short* __restrict__ xb, const unsigned short* __restrict__ msgvar,
        const float* __restrict__ Ws, const float* __restrict__ bs,
        const float* __restrict__ Wn, const float* __restrict__ bn,
        const float* __restrict__ Wv, const float* __restrict__ bv,
        float* __restrict__ out, int N) {
    __shared__ unsigned short As[64 * 200];
    int tid = threadIdx.x;
    int lane = tid & 63;
    int wv = tid >> 6;                  // feature tile (wave id)
    int j = lane & 15, quad = lane >> 4;
    int jg = wv * 16 + j;               // global output feature

    // B fragments: 6 K-steps, lane holds W[jg][k0..k0+7] as bf16
    const float* Wm0[3] = {Ws, Wn, Wv};
    bf16x8 bfrag[6];
    #pragma unroll
    for (int ks = 0; ks < 6; ++ks) {
        const float* W = Wm0[ks >> 1];
        int k0 = (ks & 1) * 32 + quad * 8;
        const float4* p = (const float4*)(W + (size_t)jg * 64 + k0);
        float4 a = p[0], b = p[1];
        bf16x8 f;
        f[0] = (short)f2bf(a.x); f[1] = (short)f2bf(a.y);
        f[2] = (short)f2bf(a.z); f[3] = (short)f2bf(a.w);
        f[4] = (short)f2bf(b.x); f[5] = (short)f2bf(b.y);
        f[6] = (short)f2bf(b.z); f[7] = (short)f2bf(b.w);
        bfrag[ks] = f;
    }
    float bias = bs[jg] + bn[jg] + bv[jg];

    #pragma unroll
    for (int t = 0; t < 2; ++t) {
        int nbase = blockIdx.x * 128 + t * 64;
        // stage x part from xb: 64 rows x 16 ushort4 (bf16 direct copy)
        #pragma unroll
        for (int i = 0; i < 4; ++i) {
            int idx = i * 256 + tid;
            int row = idx >> 4, c = idx & 15;
            int n = min(nbase + row, N - 1);
            ushort4 h = ((const ushort4*)(xb + (size_t)n * 64))[c];
            *(ushort4*)&As[row * 200 + c * 4] = h;
        }
        // stage msgvar part: 64 rows x 32 ushort4 (bf16, [msg|var] contiguous)
        #pragma unroll
        for (int i = 0; i < 8; ++i) {
            int idx = i * 256 + tid;
            int row = idx >> 5, c = idx & 31;
            int n = min(nbase + row, N - 1);
            ushort4 h = ((const ushort4*)(msgvar + (size_t)n * 128))[c];
            *(ushort4*)&As[row * 200 + 64 + c * 4] = h;
        }
        __syncthreads();

        f32x4 acc[4];
        #pragma unroll
        for (int nt = 0; nt < 4; ++nt) {
            acc[nt][0] = bias; acc[nt][1] = bias; acc[nt][2] = bias; acc[nt][3] = bias;
        }
        #pragma unroll
        for (int nt = 0; nt < 4; ++nt) {
            #pragma unroll
            for (int ks = 0; ks < 6; ++ks) {
                const bf16x8* ap = (const bf16x8*)&As[(nt * 16 + j) * 200 + ks * 32 + quad * 8];
                acc[nt] = __builtin_amdgcn_mfma_f32_16x16x32_bf16(*ap, bfrag[ks], acc[nt], 0, 0, 0);
            }
        }
        // D: node = nbase + nt*16 + quad*4 + r, col = jg
        #pragma unroll
        for (int nt = 0; nt < 4; ++nt) {
            #pragma unroll
            for (int r = 0; r < 4; ++r) {
                int node = nbase + nt * 16 + quad * 4 + r;
                if (node < N) out[(size_t)node * 64 + jg] = acc[nt][r];
            }
        }
        __syncthreads();   // protect As before next tile's staging
    }
}

extern "C" void kernel_launch(void* const* d_in, const int* in_sizes, int n_in,
                              void* d_out, int out_size, void* d_ws, size_t ws_size,
                              hipStream_t stream) {
    const float* x  = (const float*)d_in[0];
    const int*   ei = (const int*)d_in[1];
    const float* Ws = (const float*)d_in[2];
    const float* bs = (const float*)d_in[3];
    const float* Wn = (const float*)d_in[4];
    const float* bn = (const float*)d_in[5];
    const float* Wv = (const float*)d_in[6];
    const float* bv = (const float*)d_in[7];
    float* out = (float*)d_out;

    int N  = in_sizes[0] / 64;
    int E  = in_sizes[1] / 2;
    int NB = (N + 255) / 256;
    float inv4N = (float)(4.0 / (double)N);

    char* wsp = (char*)d_ws;
    size_t off = 0;
    int* deg    = (int*)(wsp + off); off += ws_align((size_t)N * 8 * 4);   // 8 copies
    int* rs     = (int*)(wsp + off); off += ws_align((size_t)(N + 1) * 4);
    int* bsumi  = (int*)(wsp + off); off += ws_align((size_t)NB * 4);
    int* srcs   = (int*)(wsp + off); off += ws_align((size_t)E * 4);
    int* rank   = (int*)(wsp + off); off += ws_align((size_t)E * 4);
    unsigned short* msgvar = (unsigned short*)(wsp + off); off += ws_align((size_t)N * 128 * 2);
    unsigned short* xb     = (unsigned short*)(wsp + off); off += ws_align((size_t)N * 64 * 2);

    int n4 = N * 16;
    hipMemsetAsync(deg, 0, (size_t)N * 8 * 4, stream);
    hist_cast_kernel<<<(max(E, n4) + 255) / 256, 256, 0, stream>>>(x, xb, ei, deg, rank, E, N, n4);
    scan_a_kernel<<<NB, 256, 0, stream>>>(deg, rs, bsumi, N);
    scan_b_kernel<<<1, 512, 0, stream>>>(bsumi, NB);
    scan_c_kernel<<<(N + 255) / 256, 256, 0, stream>>>(rs, bsumi, deg, N, E);
    scatter_kernel<<<2048, 256, 0, stream>>>(ei, deg, rank, srcs, E, N, inv4N);
    node_gather_kernel<<<((size_t)N * 64 + 255) / 256, 256, 0, stream>>>(xb, rs, srcs, msgvar, N);
    gemm_kernel<<<(N + 127) / 128, 256, 0, stream>>>(xb, msgvar, Ws, bs, Wn, bn, Wv, bv, out, N);
}